// Round 1
// baseline (2075.942 us; speedup 1.0000x reference)
//
#include <hip/hip_runtime.h>
#include <hip/hip_bf16.h>
#include <cmath>

#define T_STEPS 2048
#define BATCH   64
#define DIN     256
#define DH      256

// ---------------- Phase 1: xproj = x @ W_ih^T + (b_ih + b_hh) ----------------
// C[m][j] = sum_i x[m][i] * W_ih[j][i] + bias[j], m = t*B + b in [0, 131072)
#define P1_BM 128
#define P1_BN 128
#define P1_KC 32

__global__ __launch_bounds__(256) void xproj_kernel(
    const float* __restrict__ x, const float* __restrict__ W,
    const float* __restrict__ b_ih, const float* __restrict__ b_hh,
    float* __restrict__ out) {
  __shared__ float As[P1_BM][P1_KC + 1];   // [m][k], row stride 33
  __shared__ float Wt[P1_KC][P1_BN + 1];   // [k][j], row stride 129
  const int tid = threadIdx.x;
  const int m0 = blockIdx.x * P1_BM;
  const int j0 = blockIdx.y * P1_BN;
  const int r0 = (tid >> 4) * 8;           // 8 output rows per thread
  const int c0 = (tid & 15) * 8;           // 8 output cols per thread
  float acc[8][8] = {};

  for (int kc = 0; kc < DIN; kc += P1_KC) {
    __syncthreads();
    // stage A tile: 128 rows x 32 k, coalesced float4 loads, scalar LDS stores
#pragma unroll
    for (int s = 0; s < 4; ++s) {
      int idx = s * 256 + tid;             // 0..1023
      int row = idx >> 3;                  // 0..127
      int c4  = (idx & 7) << 2;            // 0..28
      float4 v = *reinterpret_cast<const float4*>(
          &x[(size_t)(m0 + row) * DIN + kc + c4]);
      As[row][c4 + 0] = v.x; As[row][c4 + 1] = v.y;
      As[row][c4 + 2] = v.z; As[row][c4 + 3] = v.w;
    }
    // stage W tile transposed: Wt[k][j]
#pragma unroll
    for (int s = 0; s < 4; ++s) {
      int idx = s * 256 + tid;
      int row = idx >> 3;                  // j: 0..127
      int c4  = (idx & 7) << 2;            // k: 0..28
      float4 v = *reinterpret_cast<const float4*>(
          &W[(size_t)(j0 + row) * DIN + kc + c4]);
      Wt[c4 + 0][row] = v.x; Wt[c4 + 1][row] = v.y;
      Wt[c4 + 2][row] = v.z; Wt[c4 + 3][row] = v.w;
    }
    __syncthreads();
#pragma unroll 8
    for (int k = 0; k < P1_KC; ++k) {
      float a[8], wv[8];
#pragma unroll
      for (int i = 0; i < 8; ++i) a[i] = As[r0 + i][k];
#pragma unroll
      for (int i = 0; i < 8; ++i) wv[i] = Wt[k][c0 + i];
#pragma unroll
      for (int i = 0; i < 8; ++i)
#pragma unroll
        for (int j = 0; j < 8; ++j) acc[i][j] = fmaf(a[i], wv[j], acc[i][j]);
    }
  }

  float bias[8];
#pragma unroll
  for (int j = 0; j < 8; ++j) bias[j] = b_ih[j0 + c0 + j] + b_hh[j0 + c0 + j];
#pragma unroll
  for (int i = 0; i < 8; ++i) {
    size_t m = (size_t)(m0 + r0 + i);
#pragma unroll
    for (int j4 = 0; j4 < 2; ++j4) {
      float4 v;
      v.x = acc[i][j4 * 4 + 0] + bias[j4 * 4 + 0];
      v.y = acc[i][j4 * 4 + 1] + bias[j4 * 4 + 1];
      v.z = acc[i][j4 * 4 + 2] + bias[j4 * 4 + 2];
      v.w = acc[i][j4 * 4 + 3] + bias[j4 * 4 + 3];
      *reinterpret_cast<float4*>(&out[m * DH + j0 + c0 + j4 * 4]) = v;
    }
  }
}

// ---------------- Phase 2: sequential scan, one WG per batch element --------
// h' = tanh(xproj[t][b][:] + W_hh @ h). xproj lives in the outputs region of
// d_out and is overwritten in place with h_t.
__global__ __launch_bounds__(512) void rnn_scan_kernel(
    const float* __restrict__ hx, const float* __restrict__ W_hh,
    float* __restrict__ outbuf,            // [T*B*DH], xproj in / h out
    float* __restrict__ hlast) {           // [B*DH]
  const int b   = blockIdx.x;              // batch element
  const int tid = threadIdx.x;             // 0..511
  const int jg  = tid & 63;                // j-group (wave lane)
  const int kg  = tid >> 6;                // k-group == wave id (0..7)
  const int j0  = jg * 4;
  const int k0  = kg * 32;

  // W_hh fragment in registers: 4 output rows x 32 k = 128 VGPRs
  float w[4][32];
#pragma unroll
  for (int j = 0; j < 4; ++j)
#pragma unroll
    for (int k4 = 0; k4 < 8; ++k4) {
      float4 v = *reinterpret_cast<const float4*>(
          &W_hh[(size_t)(j0 + j) * DH + k0 + k4 * 4]);
      w[j][k4 * 4 + 0] = v.x; w[j][k4 * 4 + 1] = v.y;
      w[j][k4 * 4 + 2] = v.z; w[j][k4 * 4 + 3] = v.w;
    }

  __shared__ float h_lds[DH];
  __shared__ float part[8][DH];

  if (tid < DH) h_lds[tid] = hx[(size_t)b * DH + tid];
  __syncthreads();

  const size_t stride_t = (size_t)BATCH * DH;
  const size_t base_b   = (size_t)b * DH;

  float xp_next = 0.f;
  if (tid < DH) xp_next = outbuf[base_b + tid];   // t = 0

#pragma unroll 1
  for (int t = 0; t < T_STEPS; ++t) {
    const float xp = xp_next;
    if (t + 1 < T_STEPS && tid < DH)
      xp_next = outbuf[(size_t)(t + 1) * stride_t + base_b + tid];  // prefetch

    // MVM partial: p[j] = sum_{k in my 32-chunk} w[j][k] * h[k]
    float p[4] = {0.f, 0.f, 0.f, 0.f};
#pragma unroll
    for (int k4 = 0; k4 < 8; ++k4) {
      float4 hv = *reinterpret_cast<const float4*>(&h_lds[k0 + k4 * 4]);
#pragma unroll
      for (int j = 0; j < 4; ++j) {
        p[j] = fmaf(w[j][k4 * 4 + 0], hv.x, p[j]);
        p[j] = fmaf(w[j][k4 * 4 + 1], hv.y, p[j]);
        p[j] = fmaf(w[j][k4 * 4 + 2], hv.z, p[j]);
        p[j] = fmaf(w[j][k4 * 4 + 3], hv.w, p[j]);
      }
    }
    *reinterpret_cast<float4*>(&part[kg][j0]) = make_float4(p[0], p[1], p[2], p[3]);
    __syncthreads();

    if (tid < DH) {
      float s = xp;
#pragma unroll
      for (int g = 0; g < 8; ++g) s += part[g][tid];
      const float h = tanhf(s);
      h_lds[tid] = h;
      outbuf[(size_t)t * stride_t + base_b + tid] = h;
    }
    __syncthreads();
  }

  if (tid < DH) hlast[base_b + tid] = h_lds[tid];
}

extern "C" void kernel_launch(void* const* d_in, const int* in_sizes, int n_in,
                              void* d_out, int out_size, void* d_ws, size_t ws_size,
                              hipStream_t stream) {
  const float* x    = (const float*)d_in[0];
  const float* hx   = (const float*)d_in[1];
  const float* W_ih = (const float*)d_in[2];
  const float* W_hh = (const float*)d_in[3];
  const float* b_ih = (const float*)d_in[4];
  const float* b_hh = (const float*)d_in[5];
  float* out = (float*)d_out;
  float* hlast = out + (size_t)T_STEPS * BATCH * DH;

  // Phase 1: xproj -> outputs region of d_out
  dim3 g1((T_STEPS * BATCH) / P1_BM, DH / P1_BN);
  xproj_kernel<<<g1, 256, 0, stream>>>(x, W_ih, b_ih, b_hh, out);

  // Phase 2: sequential scan, in-place over the outputs region
  rnn_scan_kernel<<<BATCH, 512, 0, stream>>>(hx, W_hh, out, hlast);
}